// Round 7
// baseline (969.176 us; speedup 1.0000x reference)
//
#include <hip/hip_runtime.h>
#include <math.h>

// Problem constants
#define BT     4096      // B*T tokens per pass
#define M_TOT  8192      // 2 passes stacked
#define KDIM   768
#define VDIM   50257
#define NBLK   393       // ceil(VDIM/128)
#define KCH    24        // 768 / 32 K-chunks
#define REWARD_SCALE 0.5
#define DIV_WEIGHT   0.1
#define EPS_COS      1e-8f
#define LOG2E        1.44269504088896340736f

typedef _Float16 half8 __attribute__((ext_vector_type(8)));
typedef float    f32x4 __attribute__((ext_vector_type(4)));

#define A_FRAGS (64*KCH*8*64)      // 786432  fragments of 16B (f16)
#define W_FRAGS (NBLK*KCH*8*64)    // 4829184 fragments of 16B

// ---------------------------------------------------------------------------
// async global->LDS, 16B per lane (wave-uniform base + lane*16 semantics)
// ---------------------------------------------------------------------------
__device__ __forceinline__ void g2l16(const short* g, short* l) {
    __builtin_amdgcn_global_load_lds(
        (const __attribute__((address_space(1))) unsigned int*)(const void*)g,
        (__attribute__((address_space(3))) unsigned int*)(void*)l,
        16, 0, 0);
}

// ---------------------------------------------------------------------------
// Converters: fp32 -> f16, pre-swizzled into MFMA fragment order (LDS
// transpose for coalesced reads).  W additionally scaled by log2(e) so
// logits come out in base-2 (epilogue exp = one v_exp_f32).
// Frag layout: ((blk*KCH + k0)*8 + tile)*64 + lane ; lane gives
//   [row = blk*128 + tile*16 + (lane&15)][k = k0*32 + (lane>>4)*8 + j]
// ---------------------------------------------------------------------------
__global__ __launch_bounds__(256)
void convert_A_kernel(const float* __restrict__ p2, const float* __restrict__ p3,
                      short* __restrict__ Ahi)
{
    __shared__ float Ls[128][36];
    const int mb = blockIdx.x;             // 0..63
    const int k0 = blockIdx.y;             // 0..23
    const int tid = threadIdx.x;

#pragma unroll
    for (int p = 0; p < 4; ++p) {
        int i = p * 1024 + tid * 4;
        int r = i >> 5;
        int c = i & 31;
        int m = mb * 128 + r;
        const float* src = (m < BT) ? (p2 + (size_t)m * KDIM)
                                    : (p3 + (size_t)(m - BT) * KDIM);
        float4 v = *(const float4*)(src + k0 * 32 + c);
        *(float4*)&Ls[r][c] = v;
    }
    __syncthreads();

    size_t base = ((size_t)(mb * KCH + k0) * 8) * 64;
#pragma unroll
    for (int h = 0; h < 2; ++h) {
        int f    = tid + h * 256;
        int lane = f & 63;
        int tile = f >> 6;
        int row  = tile * 16 + (lane & 15);
        int kq   = (lane >> 4) * 8;
        half8 out;
#pragma unroll
        for (int j = 0; j < 8; ++j) out[j] = (_Float16)Ls[row][kq + j];
        *(half8*)(Ahi + (base + f) * 8) = out;
    }
}

__global__ __launch_bounds__(256)
void convert_W_kernel(const float* __restrict__ W, short* __restrict__ Whi)
{
    __shared__ float Ls[128][36];
    const int nb = blockIdx.x;             // 0..392
    const int k0 = blockIdx.y;             // 0..23
    const int tid = threadIdx.x;

#pragma unroll
    for (int p = 0; p < 4; ++p) {
        int i = p * 1024 + tid * 4;
        int r = i >> 5;
        int c = i & 31;
        int v = nb * 128 + r;
        float4 val = make_float4(0.f, 0.f, 0.f, 0.f);
        if (v < VDIM) val = *(const float4*)(W + (size_t)v * KDIM + k0 * 32 + c);
        *(float4*)&Ls[r][c] = val;
    }
    __syncthreads();

    size_t base = ((size_t)(nb * KCH + k0) * 8) * 64;
#pragma unroll
    for (int h = 0; h < 2; ++h) {
        int f    = tid + h * 256;
        int lane = f & 63;
        int tile = f >> 6;
        int row  = tile * 16 + (lane & 15);
        int kq   = (lane >> 4) * 8;
        half8 out;
#pragma unroll
        for (int j = 0; j < 8; ++j) out[j] = (_Float16)(Ls[row][kq + j] * LOG2E);
        *(half8*)(Whi + (base + f) * 8) = out;
    }
}

// ---------------------------------------------------------------------------
// Main GEMM: 256x128 block tile, 256 threads (4 waves 2x2), wave tile 128x64.
// Rationale (r4/r5/r6 all pinned ~45% MfmaUtil with no single pipe saturated
// => aggregate L2/L3 traffic + per-phase serial overhead):
//   - 128x64 wave tile: 11.4 B/kFLOP raw operand traffic (r6: 22.9) and
//     32 MFMAs per wave per barrier phase (r6: 16).
//   - A (256 rows): global_load_lds double-buffered, 16 KB/k0, staged ONCE.
//   - B (128 cols): direct global->VGPR register-double-buffered (x2 wave
//     duplication, L1 absorbs).
//   - acc = 128 AGPR/lane; __launch_bounds__(256,2) => 2 waves/SIMD,
//     2 blocks/CU interleaving at barriers.
// ---------------------------------------------------------------------------
__global__ __launch_bounds__(256, 2)
void gemm_f16_kernel(const short* __restrict__ Ahi, const short* __restrict__ Whi,
                     double* __restrict__ g_sumexp)
{
    __shared__ __align__(16) short As[2][16][64][8];   // 32 KB
    __shared__ float rowsum[256];

    const int tid    = threadIdx.x;
    const int lane   = tid & 63;
    const int wave   = tid >> 6;      // 0..3
    const int wave_m = wave >> 1;     // 0..1  (128-row half)
    const int wave_n = wave & 1;      // 0..1  (64-col half)
    const int mb2 = blockIdx.x;       // 0..31  (256-token blocks)
    const int nb  = blockIdx.y;       // 0..392 (128-vocab blocks)

    rowsum[tid] = 0.0f;

    f32x4 acc[8][4];
#pragma unroll
    for (int i = 0; i < 8; ++i)
#pragma unroll
        for (int j = 0; j < 4; ++j) acc[i][j] = (f32x4)0.0f;

    // A frag halves: (2*mb2 + sub)*KCH*4096 + (k0*8 + tile)*512 + lane*8
    const size_t Aroot = (size_t)(2 * mb2) * KCH * 4096;
    // B frag halves: nb*KCH*4096 + k0*4096 + (wave_n*4+tn)*512 + lane*8
    const short* Bbase = Whi + (size_t)nb * KCH * 4096
                             + ((size_t)(wave_n * 4) * 64 + lane) * 8;

    // stage: 16 chunks (chunk c: A-sub c>>3, tile c&7), 4 per wave
#define STAGEA(k0_, buf_)                                                     \
    {                                                                         \
        _Pragma("unroll")                                                     \
        for (int j = 0; j < 4; ++j) {                                         \
            int c = wave * 4 + j;                                             \
            const short* gsrc = Ahi + Aroot + (size_t)(c >> 3) * KCH * 4096   \
                              + (size_t)((k0_) * 8 + (c & 7)) * 512 + lane * 8;\
            g2l16(gsrc, &As[buf_][c][lane][0]);                               \
        }                                                                     \
    }

    half8 bcur[4], bnxt[4];
    STAGEA(0, 0);
#pragma unroll
    for (int tn = 0; tn < 4; ++tn)
        bcur[tn] = *(const half8*)(Bbase + tn * 512);

#pragma unroll 2
    for (int k0 = 0; k0 < KCH; ++k0) {
        const int buf = k0 & 1;
        __syncthreads();                 // A(k0) resident (vmcnt drain here)
        if (k0 + 1 < KCH) {
            STAGEA(k0 + 1, buf ^ 1);     // hidden behind this k0's 32 MFMAs
#pragma unroll
            for (int tn = 0; tn < 4; ++tn)
                bnxt[tn] = *(const half8*)(Bbase + (size_t)(k0 + 1) * 4096
                                           + tn * 512);
        }
#pragma unroll
        for (int tm = 0; tm < 8; ++tm) {
            half8 a = *(const half8*)&As[buf][wave_m * 8 + tm][lane][0];
#pragma unroll
            for (int tn = 0; tn < 4; ++tn)
                acc[tm][tn] = __builtin_amdgcn_mfma_f32_16x16x32_f16(
                                  a, bcur[tn], acc[tm][tn], 0, 0, 0);
        }
#pragma unroll
        for (int tn = 0; tn < 4; ++tn) bcur[tn] = bnxt[tn];
    }
#undef STAGEA

    // --- epilogue: exp2 (logits pre-scaled by log2e), per-row reduce ---
    __syncthreads();
    const int colBase = nb * 128 + wave_n * 64;
    const int quad = lane >> 4;
    const int cidx = lane & 15;
#pragma unroll
    for (int tm = 0; tm < 8; ++tm) {
#pragma unroll
        for (int r = 0; r < 4; ++r) {
            float s = 0.0f;
#pragma unroll
            for (int tn = 0; tn < 4; ++tn) {
                int col = colBase + tn * 16 + cidx;
                if (col < VDIM) s += __builtin_amdgcn_exp2f(acc[tm][tn][r]);
            }
            s += __shfl_xor(s, 1);
            s += __shfl_xor(s, 2);
            s += __shfl_xor(s, 4);
            s += __shfl_xor(s, 8);
            if (cidx == 0) {
                int row = wave_m * 128 + tm * 16 + quad * 4 + r;
                atomicAdd(&rowsum[row], s);
            }
        }
    }
    __syncthreads();
    atomicAdd(&g_sumexp[(size_t)mb2 * 256 + tid], (double)rowsum[tid]);
}

// ---------------------------------------------------------------------------
// Fallback fp32 GEMM (round-2 kernel) if workspace is too small.
// ---------------------------------------------------------------------------
#define BM 128
#define BN 128
#define BK 16
#define LDPAD 4
__global__ __launch_bounds__(256)
void logits_expsum_kernel(const float* __restrict__ p2,
                          const float* __restrict__ p3,
                          const float* __restrict__ W,
                          double* __restrict__ g_sumexp)
{
    __shared__ float As[BK][BM + LDPAD];
    __shared__ float Bsh[BK][BN + LDPAD];
    __shared__ float rowsum[BM];

    const int tid     = threadIdx.x;
    const int rowBase = blockIdx.y * BM;
    const int colBase = blockIdx.x * BN;

    if (tid < BM) rowsum[tid] = 0.0f;

    float acc[8][8];
#pragma unroll
    for (int i = 0; i < 8; ++i)
#pragma unroll
        for (int j = 0; j < 8; ++j) acc[i][j] = 0.0f;

    const int ty = tid >> 4;
    const int tx = tid & 15;
    const int r0 = ty * 8;
    const int c0 = tx * 4;

    for (int k0 = 0; k0 < KDIM; k0 += BK) {
        __syncthreads();
#pragma unroll
        for (int l = 0; l < 2; ++l) {
            int id  = tid + l * 256;
            int row = id >> 2;
            int kq  = id & 3;
            int m   = rowBase + row;
            const float* src = (m < BT) ? (p2 + (size_t)m * KDIM)
                                        : (p3 + (size_t)(m - BT) * KDIM);
            float4 v = *(const float4*)(src + k0 + kq * 4);
            As[kq * 4 + 0][row] = v.x;
            As[kq * 4 + 1][row] = v.y;
            As[kq * 4 + 2][row] = v.z;
            As[kq * 4 + 3][row] = v.w;
        }
#pragma unroll
        for (int l = 0; l < 2; ++l) {
            int id  = tid + l * 256;
            int row = id >> 2;
            int kq  = id & 3;
            int c   = colBase + row;
            int cs  = (c < VDIM) ? c : (VDIM - 1);
            float4 v = *(const float4*)(W + (size_t)cs * KDIM + k0 + kq * 4);
            Bsh[kq * 4 + 0][row] = v.x;
            Bsh[kq * 4 + 1][row] = v.y;
            Bsh[kq * 4 + 2][row] = v.z;
            Bsh[kq * 4 + 3][row] = v.w;
        }
        __syncthreads();
#pragma unroll
        for (int kk = 0; kk < BK; ++kk) {
            float a[8], bb[8];
            *(float4*)&a[0]  = *(const float4*)&As[kk][r0];
            *(float4*)&a[4]  = *(const float4*)&As[kk][r0 + 4];
            *(float4*)&bb[0] = *(const float4*)&Bsh[kk][c0];
            *(float4*)&bb[4] = *(const float4*)&Bsh[kk][64 + c0];
#pragma unroll
            for (int i = 0; i < 8; ++i)
#pragma unroll
                for (int j = 0; j < 8; ++j)
                    acc[i][j] = fmaf(a[i], bb[j], acc[i][j]);
        }
    }

    __syncthreads();
#pragma unroll
    for (int i = 0; i < 8; ++i) {
        float s = 0.0f;
#pragma unroll
        for (int j = 0; j < 8; ++j) {
            int c = colBase + ((j < 4) ? (c0 + j) : (64 + c0 + (j - 4)));
            if (c < VDIM) s += expf(acc[i][j]);
        }
        atomicAdd(&rowsum[r0 + i], s);
    }
    __syncthreads();
    if (tid < BM) {
        atomicAdd(&g_sumexp[rowBase + tid], (double)rowsum[tid]);
    }
}

// ---------------------------------------------------------------------------
// Kernel 2: per token — GEMM-INDEPENDENT dots (target logit, cosine).
// tokvals[t] = {s2w, s3w, cos, valid}.  No atomics, no g_sumexp.
// ---------------------------------------------------------------------------
__global__ __launch_bounds__(256)
void finalize_dots_kernel(const float* __restrict__ p2,
                          const float* __restrict__ p3,
                          const float* __restrict__ W,
                          const int*   __restrict__ targets,
                          double* __restrict__ tokvals)
{
    const int t   = blockIdx.x;
    const int tid = threadIdx.x;
    const int tg  = targets[t];
    const bool valid = (tg >= 0);
    const float* w = W + (size_t)(valid ? tg : 0) * KDIM;
    const float* a = p2 + (size_t)t * KDIM;
    const float* b = p3 + (size_t)t * KDIM;

    float s22 = 0.f, s33 = 0.f, s23 = 0.f, s2w = 0.f, s3w = 0.f;
    for (int i = tid; i < KDIM; i += 256) {
        float x = a[i], y = b[i], ww = w[i];
        s22 = fmaf(x, x, s22);
        s33 = fmaf(y, y, s33);
        s23 = fmaf(x, y, s23);
        s2w = fmaf(x, ww, s2w);
        s3w = fmaf(y, ww, s3w);
    }
#pragma unroll
    for (int off = 32; off > 0; off >>= 1) {
        s22 += __shfl_down(s22, off);
        s33 += __shfl_down(s33, off);
        s23 += __shfl_down(s23, off);
        s2w += __shfl_down(s2w, off);
        s3w += __shfl_down(s3w, off);
    }
    __shared__ float sm[5][4];
    const int wv = tid >> 6, lane = tid & 63;
    if (lane == 0) {
        sm[0][wv] = s22; sm[1][wv] = s33; sm[2][wv] = s23;
        sm[3][wv] = s2w; sm[4][wv] = s3w;
    }
    __syncthreads();
    if (tid == 0) {
        float S22 = sm[0][0] + sm[0][1] + sm[0][2] + sm[0][3];
        float S33 = sm[1][0] + sm[1][1] + sm[1][2] + sm[1][3];
        float S23 = sm[2][0] + sm[2][1] + sm[2][2] + sm[2][3];
        float S2w = sm[3][0] + sm[3][1] + sm[3][2] + sm[3][3];
        float S3w = sm[4][0] + sm[4][1] + sm[4][2] + sm[4][3];

        float n2 = fmaxf(sqrtf(S22), EPS_COS);
        float n3 = fmaxf(sqrtf(S33), EPS_COS);

        double4 out;
        out.x = (double)S2w;
        out.y = (double)S3w;
        out.z = (double)(S23 / (n2 * n3));
        out.w = valid ? 1.0 : 0.0;
        *(double4*)(tokvals + 4 * (size_t)t) = out;
    }
}

// ---------------------------------------------------------------------------
// Kernel 3: post-GEMM tail — nll from dots + log(sumexp), full reduce.
// ---------------------------------------------------------------------------
__global__ __launch_bounds__(1024)
void final_scalar_kernel(const double* __restrict__ tokvals,
                         const double* __restrict__ g_sumexp,
                         float* __restrict__ out)
{
    const int tid = threadIdx.x;
    double s0 = 0.0, s1 = 0.0, s2 = 0.0, s3 = 0.0;
    for (int t = tid; t < BT; t += 1024) {
        double4 v = *(const double4*)(tokvals + 4 * (size_t)t);
        if (v.w > 0.0) {
            s0 += log(g_sumexp[t])      - v.x;
            s1 += log(g_sumexp[BT + t]) - v.y;
            s3 += 1.0;
        }
        s2 += v.z;
    }
#pragma unroll
    for (int off = 32; off > 0; off >>= 1) {
        s0 += __shfl_down(s0, off);
        s1 += __shfl_down(s1, off);
        s2 += __shfl_down(s2, off);
        s3 += __shfl_down(s3, off);
    }
    __shared__ double sm[4][16];
    const int wv = tid >> 6, lane = tid & 63;
    if (lane == 0) { sm[0][wv] = s0; sm[1][wv] = s1; sm[2][wv] = s2; sm[3][wv] = s3; }
    __syncthreads();
    if (tid == 0) {
        double S0 = 0, S1 = 0, S2 = 0, S3 = 0;
#pragma unroll
        for (int i = 0; i < 16; ++i) { S0 += sm[0][i]; S1 += sm[1][i]; S2 += sm[2][i]; S3 += sm[3][i]; }
        double cnt = (S3 > 0.0) ? S3 : 1.0;
        double loss_p2 = S0 / cnt;
        double loss_p3 = S1 / cnt;
        double reward_loss = -REWARD_SCALE * (loss_p2 - loss_p3);
        double divergence  =  DIV_WEIGHT * (S2 / (double)BT);
        out[0] = (float)(reward_loss + divergence);
    }
}

// ---------------------------------------------------------------------------
extern "C" void kernel_launch(void* const* d_in, const int* in_sizes, int n_in,
                              void* d_out, int out_size, void* d_ws, size_t ws_size,
                              hipStream_t stream)
{
    const float* p2  = (const float*)d_in[0];   // [2,2048,768] fp32
    const float* p3  = (const float*)d_in[1];   // [2,2048,768] fp32
    const float* W   = (const float*)d_in[2];   // [50257,768] fp32
    const int*   tgt = (const int*)d_in[3];     // [2,2048]

    double* g_sumexp = (double*)d_ws;                    // 8192 doubles (64 KB)
    double* tokvals  = g_sumexp + M_TOT;                 // 16384 doubles (128 KB)
    char*   fragbase = (char*)d_ws + 196608;

    hipMemsetAsync(d_ws, 0, 65536, stream);   // g_sumexp only

    const size_t need = 196608 + (size_t)A_FRAGS * 16 + (size_t)W_FRAGS * 16;
    if (ws_size >= need) {
        short* Ahi = (short*)fragbase;
        short* Whi = Ahi + (size_t)A_FRAGS * 8;

        convert_A_kernel<<<dim3(64, KCH), dim3(256), 0, stream>>>(p2, p3, Ahi);
        convert_W_kernel<<<dim3(NBLK, KCH), dim3(256), 0, stream>>>(W, Whi);
        finalize_dots_kernel<<<dim3(BT), dim3(256), 0, stream>>>(p2, p3, W, tgt, tokvals);
        gemm_f16_kernel<<<dim3(32, NBLK), dim3(256), 0, stream>>>(Ahi, Whi, g_sumexp);
        final_scalar_kernel<<<dim3(1), dim3(1024), 0, stream>>>(tokvals, g_sumexp, (float*)d_out);
    } else {
        logits_expsum_kernel<<<dim3(NBLK, 64), dim3(256), 0, stream>>>(p2, p3, W, g_sumexp);
        finalize_dots_kernel<<<dim3(BT), dim3(256), 0, stream>>>(p2, p3, W, tgt, tokvals);
        final_scalar_kernel<<<dim3(1), dim3(1024), 0, stream>>>(tokvals, g_sumexp, (float*)d_out);
    }
}